// Round 1
// 217.633 us; speedup vs baseline: 1.0349x; 1.0349x over previous
//
#include <hip/hip_runtime.h>
#include <cstdint>
#include <cstddef>

#define RHO 1e-8f
#define EPSV 1e-8f
#define THRESH 0.9f

typedef float v2f __attribute__((ext_vector_type(2)));

__device__ __forceinline__ float wave_max(float v) {
#pragma unroll
  for (int off = 1; off < 64; off <<= 1) v = fmaxf(v, __shfl_xor(v, off, 64));
  return v;
}

// ---------------- Stage 1: outer_forward -> (maxval, argmax) per (f, b) ------
// 2 waves/block, one field per wave, lane = mem row, NO barriers.
// The per-field x tile (32 b x 64 d, 8 KB) is staged ONCE into a wave-private
// LDS strip (row stride 68 floats: keeps float4 16B alignment; staging
// ds_write_b128 and norm ds_read_b128 are both conflict-OPTIMAL, b-loop row
// reads are uniform broadcasts). This removes the per-iteration global x-row
// round trip that made the old kernel latency-bound (VALUBusy 21%).
// Iteration b overwrites its consumed x row with the 64 vals -> the same
// strip doubles as the transpose buffer for the final argmax (LDS stays
// 17.4 KB/block -> 8 blocks/CU, 16 waves/CU).
__global__ __launch_bounds__(128) void stage1_kernel(
    const float* __restrict__ xs, const float* __restrict__ mm0,
    float* __restrict__ maxv1, int* __restrict__ idx1) {
  const int lane = threadIdx.x & 63;
  const int wave = threadIdx.x >> 6;
  const int f = __builtin_amdgcn_readfirstlane(blockIdx.x * 2 + wave);

  __shared__ float sbuf[2][32 * 68];  // 17,408 B total; wave-private strips
  float* sb = sbuf[wave];

  // ---- stage x tile: iter i, lane L -> g = i*64+L; b = g>>4; dq = g&15.
  // Global: 16-lane groups read contiguous 256B segments (coalesced).
  // LDS: dword bank = 4*(b+dq) % 32 -> 8 disjoint bank-quads, 8 lanes each
  // -> exactly the minimum 8 rounds per ds_write_b128 (conflict-free).
  const float* xf = xs + (size_t)f * 64;
#pragma unroll
  for (int i = 0; i < 8; ++i) {
    const int g = i * 64 + lane;
    const int b = g >> 4, dq = g & 15;
    const float4 v = *reinterpret_cast<const float4*>(
        xf + (size_t)b * (4096 * 64) + dq * 4);
    *reinterpret_cast<float4*>(&sb[b * 68 + dq * 4]) = v;
  }

  // ---- my memory row (mem = lane), shifted by -0.5 ----
  const float4* mrow =
      reinterpret_cast<const float4*>(mm0 + ((size_t)f * 64 + lane) * 64);
  v2f m2[32];
#pragma unroll
  for (int j = 0; j < 16; ++j) {
    float4 v = mrow[j];
    m2[2 * j] = (v2f){v.x - 0.5f, v.y - 0.5f};
    m2[2 * j + 1] = (v2f){v.z - 0.5f, v.w - 0.5f};
  }
  v2f mn2 = {0.f, 0.f}, sm2 = {0.f, 0.f};
#pragma unroll
  for (int j = 0; j < 32; ++j) {
    mn2 = m2[j] * m2[j] + mn2;
    sm2 = sm2 + m2[j];
  }
  const float mn = sqrtf(mn2.x + mn2.y);
  const float sm = sm2.x + sm2.y;

  // ---- x-row norms from LDS: lane handles b = lane&31 (high half dups
  // read the same addresses -> broadcast-merged, free). Per instruction the
  // 32 distinct lanes hit 8 bank-quads x 4 lanes = the minimum 4 rounds.
  float xnv;
  {
    const int b = lane & 31;
    const float* xr = &sb[b * 68];
    v2f s2 = {0.f, 0.f}, s1 = {0.f, 0.f};
#pragma unroll
    for (int j = 0; j < 16; ++j) {
      float4 v = *reinterpret_cast<const float4*>(xr + j * 4);
      v2f p0 = {v.x, v.y}, p1 = {v.z, v.w};
      s2 = p0 * p0 + s2;
      s2 = p1 * p1 + s2;
      s1 = s1 + p0 + p1;
    }
    xnv = sqrtf(s2.x + s2.y - (s1.x + s1.y) + 16.f);
  }

  // ---- b-loop: uniform LDS row reads (broadcast), FMA against register
  // m-tile; then overwrite the just-consumed row b with this batch's vals
  // (vb[b][mem]) for the transpose-read argmax below.
#pragma clang loop unroll_count(2)
  for (int b = 0; b < 32; ++b) {
    const float* xq = &sb[b * 68];
    const float xnb =
        __int_as_float(__builtin_amdgcn_readlane(__float_as_int(xnv), b));
    v2f a0 = {0.f, 0.f}, a1 = {0.f, 0.f}, a2 = {0.f, 0.f}, a3 = {0.f, 0.f};
#pragma unroll
    for (int j = 0; j < 16; j += 4) {
      float4 q0 = *reinterpret_cast<const float4*>(xq + 4 * j);
      float4 q1 = *reinterpret_cast<const float4*>(xq + 4 * (j + 1));
      float4 q2 = *reinterpret_cast<const float4*>(xq + 4 * (j + 2));
      float4 q3 = *reinterpret_cast<const float4*>(xq + 4 * (j + 3));
      a0 = m2[2 * j + 0] * (v2f){q0.x, q0.y} + a0;
      a0 = m2[2 * j + 1] * (v2f){q0.z, q0.w} + a0;
      a1 = m2[2 * j + 2] * (v2f){q1.x, q1.y} + a1;
      a1 = m2[2 * j + 3] * (v2f){q1.z, q1.w} + a1;
      a2 = m2[2 * j + 4] * (v2f){q2.x, q2.y} + a2;
      a2 = m2[2 * j + 5] * (v2f){q2.z, q2.w} + a2;
      a3 = m2[2 * j + 6] * (v2f){q3.x, q3.y} + a3;
      a3 = m2[2 * j + 7] * (v2f){q3.z, q3.w} + a3;
    }
    v2f as = (a0 + a1) + (a2 + a3);
    const float acc = as.x + as.y - 0.5f * sm;  // dot(m-0.5, x-0.5)
    const float val = (acc * 0.5f) / (mn * xnb + RHO) + 0.5f;
    sb[b * 68 + lane] = val;  // bank (4b+lane)%32: 2-way, free
  }

  // ---- transpose-read: lane handles batch (lane&31), rows half*32..+31.
  // (8-way bank aliasing here: 32 scalar reads, ~200 cy -- negligible.)
  const int bb = lane & 31, half = lane >> 5;
  float best = -__builtin_inff();
  int bi = 0;
#pragma unroll
  for (int j = 0; j < 32; ++j) {
    float v = sb[bb * 68 + half * 32 + j];
    if (v > best) { best = v; bi = half * 32 + j; }
  }
  const float ov = __shfl_xor(best, 32, 64);
  const int oi = __shfl_xor(bi, 32, 64);
  const bool lo = (half == 0);
  const float bl = lo ? best : ov;
  const int il = lo ? bi : oi;
  const float bh = lo ? ov : best;
  const int ih = lo ? oi : bi;
  const float fb = (bl >= bh) ? bl : bh;  // ties -> low half -> first index
  const int fi = (bl >= bh) ? il : ih;
  if (lane < 32) {
    maxv1[f * 32 + lane] = fb;
    idx1[f * 32 + lane] = fi;
  }
}

// ---------------- Stage 2: hidden_forward (512 nodes) -------------------------
// Block = node. mm1 slice (128 KB) streamed coalesced ONCE through a 64 KB
// XOR-swizzled column-major LDS tile (4 children per phase, 2 phases).
// Element (c,h,k) lives at tile[c*4096 + k*64 + (h^k)]: staging writes and
// column reads are both <=2-way bank aliasing (free). Inputs [field][b].
__global__ __launch_bounds__(256) void stage2_kernel(
    const float* __restrict__ maxv_in, const int* __restrict__ idx_in,
    const float* __restrict__ mm,
    float* __restrict__ maxv_out, int* __restrict__ idx_out) {
  const int node = blockIdx.x;
  const int lane = threadIdx.x & 63;
  const int wave = threadIdx.x >> 6;
  const int tid = threadIdx.x;

  __shared__ float tile[4 * 4096];  // 65,536 B exactly

  const float4* src = reinterpret_cast<const float4*>(mm + (size_t)node * (8 * 4096));

  float acc[8], s2[8];
#pragma unroll
  for (int i = 0; i < 8; ++i) { acc[i] = 0.f; s2[i] = 0.f; }

#pragma clang loop unroll_count(1)
  for (int phase = 0; phase < 2; ++phase) {
    if (phase) __syncthreads();  // protect previous compute before overwrite
#pragma unroll
    for (int i = 0; i < 16; ++i) {
      int g = tid + 256 * i;  // [0, 4096) float4s over 4 children
      float4 v = src[phase * 4096 + g];
      int cl = g >> 10, rem = g & 1023;
      int h = rem >> 4, k0 = (rem & 15) * 4;
      float* base = &tile[cl * 4096];
      base[(k0 + 0) * 64 + (h ^ (k0 + 0))] = v.x;
      base[(k0 + 1) * 64 + (h ^ (k0 + 1))] = v.y;
      base[(k0 + 2) * 64 + (h ^ (k0 + 2))] = v.z;
      base[(k0 + 3) * 64 + (h ^ (k0 + 3))] = v.w;
    }
    __syncthreads();
#pragma unroll
    for (int i = 0; i < 8; ++i) {
      const int b = wave * 8 + i;
#pragma unroll
      for (int cl = 0; cl < 4; ++cl) {
        const int c = phase * 4 + cl;
        const int off = __builtin_amdgcn_readfirstlane((node * 8 + c) * 32 + b);
        const int k = idx_in[off];
        const float v = maxv_in[off];
        const float w = tile[cl * 4096 + k * 64 + (lane ^ k)];
        acc[i] = fmaf(w, v, acc[i]);
        s2[i] = fmaf(v, v, s2[i]);
      }
    }
  }

#pragma unroll
  for (int i = 0; i < 8; ++i) {
    const int b = wave * 8 + i;
    const float val = acc[i] / (8.f * sqrtf(s2[i]) + RHO);
    const float mx = wave_max(val);
    unsigned long long t = __ballot(val == mx);
    int j0 = __ffsll((long long)t) - 1;
    if (lane == 0) {
      maxv_out[node * 32 + b] = mx;  // [node][b]
      idx_out[node * 32 + b] = j0;
    }
  }
}

// ---------------- Stage 3 + growth_argmaxi (fused; exact since round 1) -------
__global__ __launch_bounds__(256) void grow_kernel(
    const float* __restrict__ maxv_in, const int* __restrict__ idx_in,
    const float* __restrict__ mm,
    const float* __restrict__ counts, float* __restrict__ out) {
  const int node = blockIdx.x;  // 64 nodes
  const int lane = threadIdx.x & 63;
  const int wave = threadIdx.x >> 6;
  const int tid = threadIdx.x;

  __shared__ float tile[2 * 4096];  // 32 KB, 2 children per phase
  __shared__ float hbuf[32 * 64];
  __shared__ float mxvS[32];
  __shared__ int idxS[32];
  __shared__ int trgS[32];
  __shared__ float cntS[64];
  __shared__ int sidxS[64];
  __shared__ int flagS[64];
  __shared__ int compS[64];
  __shared__ int selS[32];
  __shared__ float valS[32];
  __shared__ int keptS[1];

  const float4* src = reinterpret_cast<const float4*>(mm + (size_t)node * (8 * 4096));

  float acc[8], s2[8];
#pragma unroll
  for (int i = 0; i < 8; ++i) { acc[i] = 0.f; s2[i] = 0.f; }

#pragma clang loop unroll_count(1)
  for (int phase = 0; phase < 4; ++phase) {
    if (phase) __syncthreads();
#pragma unroll
    for (int i = 0; i < 8; ++i) {
      int g = tid + 256 * i;  // [0, 2048) float4s over 2 children
      float4 v = src[phase * 2048 + g];
      int cl = g >> 10, rem = g & 1023;
      int h = rem >> 4, k0 = (rem & 15) * 4;
      float* base = &tile[cl * 4096];
      base[(k0 + 0) * 64 + (h ^ (k0 + 0))] = v.x;
      base[(k0 + 1) * 64 + (h ^ (k0 + 1))] = v.y;
      base[(k0 + 2) * 64 + (h ^ (k0 + 2))] = v.z;
      base[(k0 + 3) * 64 + (h ^ (k0 + 3))] = v.w;
    }
    __syncthreads();
#pragma unroll
    for (int i = 0; i < 8; ++i) {
      const int b = wave * 8 + i;
#pragma unroll
      for (int cl = 0; cl < 2; ++cl) {
        const int c = phase * 2 + cl;
        const int off = __builtin_amdgcn_readfirstlane((node * 8 + c) * 32 + b);
        const int k = idx_in[off];
        const float v = maxv_in[off];
        const float w = tile[cl * 4096 + k * 64 + (lane ^ k)];
        acc[i] = fmaf(w, v, acc[i]);
        s2[i] = fmaf(v, v, s2[i]);
      }
    }
  }

#pragma unroll
  for (int i = 0; i < 8; ++i) {
    const int b = wave * 8 + i;
    const float val = acc[i] / (8.f * sqrtf(s2[i]) + RHO);
    const float mx = wave_max(val);
    unsigned long long t = __ballot(val == mx);
    int j0 = __ffsll((long long)t) - 1;
    hbuf[b * 64 + lane] = val;
    unsigned long long big = __ballot(val > THRESH);
    if (lane == 0) {
      mxvS[b] = mx; idxS[b] = j0; trgS[b] = (big == 0ULL) ? 1 : 0;
    }
  }

  if (tid < 64) { cntS[tid] = counts[node * 64 + tid]; flagS[tid] = 0; }
  __syncthreads();
  if (tid < 64) {  // stable ascending argsort of counts row
    float cl = cntS[tid];
    int rank = 0;
    for (int j = 0; j < 64; ++j) {
      float cj = cntS[j];
      rank += (cj < cl || (cj == cl && j < tid)) ? 1 : 0;
    }
    sidxS[rank] = tid;
  }
  __syncthreads();
  if (tid < 32) {  // reserved marks from non-triggered batches
    const int b = tid;
    if (!trgS[b]) {
      int j = idxS[b];
      float a = fabsf(mxvS[b]);
      int res;
      if (a > EPSV) res = j;             // unique positive max -> argsort[-1]=j
      else if (a == 0.f) res = 63;       // all-zero row: stable last = 63
      else if (a == EPSV) res = j;       // +inf at j
      else res = (j == 63) ? 62 : 63;    // negative entry: last zero wins
      flagS[res] = 1;
    }
  }
  __syncthreads();
  if (wave == 0) {  // stable compaction (move MARK to back)
    int s = sidxS[lane];
    int keep = flagS[s] ? 0 : 1;
    unsigned long long kb = __ballot(keep);
    int pos = __popcll(kb & ((1ULL << lane) - 1ULL));
    if (keep) compS[pos] = s;
    if (lane == 0) keptS[0] = __popcll(kb);
  }
  __syncthreads();
  if (tid < 32) {  // final index + value per batch
    const int b = tid;
    int fin = (b < keptS[0]) ? compS[b] : sidxS[b];
    int idxb; float a;
    if (trgS[b]) {
      idxb = fin;
      float v = hbuf[b * 64 + idxb];
      if (v == 0.f) v = 1.f;
      a = fabsf(v);
    } else {
      idxb = idxS[b];
      a = fabsf(mxvS[b]);
    }
    selS[b] = idxb;
    valS[b] = a / (a - EPSV);
  }
  __syncthreads();
#pragma unroll
  for (int r = 0; r < 8; ++r) {  // write (32,64) one-hot rows for this node
    int i = tid + 256 * r;
    int b = i >> 6, h = i & 63;
    out[((size_t)b * 64 + node) * 64 + h] = (h == selS[b]) ? valS[b] : 0.f;
  }
}

extern "C" void kernel_launch(void* const* d_in, const int* in_sizes, int n_in,
                              void* d_out, int out_size, void* d_ws, size_t ws_size,
                              hipStream_t stream) {
  const float* xs = (const float*)d_in[0];      // (32, 4096, 64)
  const float* mm0 = (const float*)d_in[1];     // (4096, 64, 64)
  const float* mm1 = (const float*)d_in[2];     // (512, 8, 64, 64)
  const float* mm2 = (const float*)d_in[3];     // (64, 8, 64, 64)
  const float* counts = (const float*)d_in[4];  // (64, 64)
  float* out = (float*)d_out;                   // (32, 64, 64)
  char* ws = (char*)d_ws;

  float* maxv1 = (float*)(ws + 0);        // [4096][32] f32
  int* idx1 = (int*)(ws + 524288);        // [4096][32] i32
  float* maxv2 = (float*)(ws + 1048576);  // [512][32] f32
  int* idx2 = (int*)(ws + 1114112);       // [512][32] i32

  stage1_kernel<<<dim3(2048), dim3(128), 0, stream>>>(xs, mm0, maxv1, idx1);
  stage2_kernel<<<dim3(512), dim3(256), 0, stream>>>(maxv1, idx1, mm1, maxv2, idx2);
  grow_kernel<<<dim3(64), dim3(256), 0, stream>>>(maxv2, idx2, mm2, counts, out);
}

// Round 2
// 215.008 us; speedup vs baseline: 1.0475x; 1.0122x over previous
//
#include <hip/hip_runtime.h>
#include <cstdint>
#include <cstddef>

#define RHO 1e-8f
#define EPSV 1e-8f
#define THRESH 0.9f

typedef float v2f __attribute__((ext_vector_type(2)));

__device__ __forceinline__ float wave_max(float v) {
#pragma unroll
  for (int off = 1; off < 64; off <<= 1) v = fmaxf(v, __shfl_xor(v, off, 64));
  return v;
}

// ---------------- Stage 1: outer_forward -> (maxval, argmax) per (f, b) ------
// v2: register-blocked GEMM. Round-1 post-mortem: the broadcast x-row LDS
// reads were RF-writeback-bound (512 ds_read_b128/wave, each delivering 1 KB
// of 64x-duplicated data -> ~98k cy/CU, matching the 132k-cy kernel).
// Now: per field (one wave), C[64m][32b] is tiled 8m x 4b per lane over an
// 8x8 lane grid with INTERLEAVED rows (m = mg+8i, b = bg+8j). Both operands
// stream from LDS with per-lane-distinct addresses: 12 ds_read_b128 per
// K-chunk of 4 (192/wave, 2.7x less + no 64x duplication). With row stride
// 68 and interleaved tiling, each read's 8 unique addrs hit 8 distinct
// bank-quads (1 round; duplicate lanes broadcast-merge). m is staged with
// -0.5 applied so the inner loop is a pure dot product.
__global__ __launch_bounds__(128) void stage1_kernel(
    const float* __restrict__ xs, const float* __restrict__ mm0,
    float* __restrict__ maxv1, int* __restrict__ idx1) {
  const int lane = threadIdx.x & 63;
  const int wave = threadIdx.x >> 6;
  const int f = __builtin_amdgcn_readfirstlane(blockIdx.x * 2 + wave);

  __shared__ float mbuf[2][64 * 68];  // 34,816 B (m - 0.5, row stride 68)
  __shared__ float xbuf[2][32 * 68];  // 17,408 B (x - 0.5)
  float* mb = mbuf[wave];
  float* xb = xbuf[wave];

  // ---- stage m tile (16 KB), shifted by -0.5, coalesced 1 KB/instr ----
  const float* mf = mm0 + (size_t)f * 4096;
#pragma unroll
  for (int i = 0; i < 16; ++i) {
    const int g = i * 64 + lane;
    const int r = g >> 4, dq = g & 15;
    float4 v = *reinterpret_cast<const float4*>(mf + r * 64 + dq * 4);
    float4 w = {v.x - 0.5f, v.y - 0.5f, v.z - 0.5f, v.w - 0.5f};
    *reinterpret_cast<float4*>(&mb[r * 68 + dq * 4]) = w;
  }
  // ---- stage x tile (8 KB), shifted by -0.5 ----
  const float* xf = xs + (size_t)f * 64;
#pragma unroll
  for (int i = 0; i < 8; ++i) {
    const int g = i * 64 + lane;
    const int b = g >> 4, dq = g & 15;
    float4 v = *reinterpret_cast<const float4*>(xf + (size_t)b * (4096 * 64) + dq * 4);
    float4 w = {v.x - 0.5f, v.y - 0.5f, v.z - 0.5f, v.w - 0.5f};
    *reinterpret_cast<float4*>(&xb[b * 68 + dq * 4]) = w;
  }

  // ---- norms: lane computes ||m2[lane]||; lane computes ||x2[lane&31]|| ----
  float mnv, xnv;
  {
    v2f s = {0.f, 0.f};
    const float* mr = &mb[lane * 68];
#pragma unroll
    for (int j = 0; j < 16; ++j) {
      float4 v = *reinterpret_cast<const float4*>(mr + 4 * j);
      s = (v2f){v.x, v.y} * (v2f){v.x, v.y} + s;
      s = (v2f){v.z, v.w} * (v2f){v.z, v.w} + s;
    }
    mnv = sqrtf(s.x + s.y);
  }
  {
    v2f s = {0.f, 0.f};
    const float* xr = &xb[(lane & 31) * 68];
#pragma unroll
    for (int j = 0; j < 16; ++j) {
      float4 v = *reinterpret_cast<const float4*>(xr + 4 * j);
      s = (v2f){v.x, v.y} * (v2f){v.x, v.y} + s;
      s = (v2f){v.z, v.w} * (v2f){v.z, v.w} + s;
    }
    xnv = sqrtf(s.x + s.y);
  }

  // ---- K-loop: 16 chunks of 4 dims; 8 a-reads + 4 b-reads + 64 pk_fma ----
  const int mg = lane >> 3, bg = lane & 7;
  v2f acc[8][4][2];
#pragma unroll
  for (int i = 0; i < 8; ++i)
#pragma unroll
    for (int j = 0; j < 4; ++j) {
      acc[i][j][0] = (v2f){0.f, 0.f};
      acc[i][j][1] = (v2f){0.f, 0.f};
    }

#pragma unroll
  for (int d0 = 0; d0 < 64; d0 += 4) {
    float4 a[8], bx[4];
#pragma unroll
    for (int i = 0; i < 8; ++i)
      a[i] = *reinterpret_cast<const float4*>(&mb[(mg + 8 * i) * 68 + d0]);
#pragma unroll
    for (int j = 0; j < 4; ++j)
      bx[j] = *reinterpret_cast<const float4*>(&xb[(bg + 8 * j) * 68 + d0]);
#pragma unroll
    for (int i = 0; i < 8; ++i)
#pragma unroll
      for (int j = 0; j < 4; ++j) {
        acc[i][j][0] = (v2f){a[i].x, a[i].y} * (v2f){bx[j].x, bx[j].y} + acc[i][j][0];
        acc[i][j][1] = (v2f){a[i].z, a[i].w} * (v2f){bx[j].z, bx[j].w} + acc[i][j][1];
      }
  }

  // ---- gather needed norms via shuffles ----
  float mn_i[8], xn_j[4];
#pragma unroll
  for (int i = 0; i < 8; ++i) mn_i[i] = __shfl(mnv, mg + 8 * i, 64);
#pragma unroll
  for (int j = 0; j < 4; ++j) xn_j[j] = __shfl(xnv, bg + 8 * j, 64);

  // ---- vals + in-lane argmax over i (m = mg+8i, ascending -> first-max) ----
  float best[4];
  int bidx[4];
#pragma unroll
  for (int j = 0; j < 4; ++j) { best[j] = -__builtin_inff(); bidx[j] = 0; }
#pragma unroll
  for (int i = 0; i < 8; ++i)
#pragma unroll
    for (int j = 0; j < 4; ++j) {
      const float dot =
          acc[i][j][0].x + acc[i][j][0].y + acc[i][j][1].x + acc[i][j][1].y;
      const float val = (dot * 0.5f) / (mn_i[i] * xn_j[j] + RHO) + 0.5f;
      if (val > best[j]) { best[j] = val; bidx[j] = mg + 8 * i; }
    }
  // ---- cross-lane argmax over mg (lanes stride 8); ties -> lower m ----
#pragma unroll
  for (int off = 8; off < 64; off <<= 1) {
#pragma unroll
    for (int j = 0; j < 4; ++j) {
      const float pv = __shfl_xor(best[j], off, 64);
      const int pm = __shfl_xor(bidx[j], off, 64);
      if (pv > best[j] || (pv == best[j] && pm < bidx[j])) {
        best[j] = pv; bidx[j] = pm;
      }
    }
  }
  if (mg == 0) {
#pragma unroll
    for (int j = 0; j < 4; ++j) {
      const int b = bg + 8 * j;
      maxv1[f * 32 + b] = best[j];
      idx1[f * 32 + b] = bidx[j];
    }
  }
}

// -------- shared pipeline macros for stage2/grow (1 child = 16 KB tile) -----
// Swizzled layout per child: element (h,k) at [k*64 + (h^k)] -> staging
// writes and per-(b) column reads are conflict-free.
#define STAGE_WRITE(T, R)                                    \
  do {                                                       \
    _Pragma("unroll") for (int i_ = 0; i_ < 4; ++i_) {       \
      const int g_ = tid + 256 * i_;                         \
      const int h_ = g_ >> 4, k0_ = (g_ & 15) * 4;           \
      (T)[(k0_ + 0) * 64 + (h_ ^ (k0_ + 0))] = (R)[i_].x;    \
      (T)[(k0_ + 1) * 64 + (h_ ^ (k0_ + 1))] = (R)[i_].y;    \
      (T)[(k0_ + 2) * 64 + (h_ ^ (k0_ + 2))] = (R)[i_].z;    \
      (T)[(k0_ + 3) * 64 + (h_ ^ (k0_ + 3))] = (R)[i_].w;    \
    }                                                        \
  } while (0)

#define LOAD_CHILD(R, C)                                     \
  do {                                                       \
    _Pragma("unroll") for (int i_ = 0; i_ < 4; ++i_)         \
        (R)[i_] = src[(C) * 1024 + tid + 256 * i_];          \
  } while (0)

#define COMPUTE_CHILD(C, T)                                              \
  do {                                                                   \
    _Pragma("unroll") for (int i_ = 0; i_ < 8; ++i_) {                   \
      const int b_ = wave * 8 + i_;                                      \
      const int off_ =                                                   \
          __builtin_amdgcn_readfirstlane((node * 8 + (C)) * 32 + b_);    \
      const int k_ = idx_in[off_];                                       \
      const float v_ = maxv_in[off_];                                    \
      const float w_ = (T)[k_ * 64 + (lane ^ k_)];                       \
      acc[i_] = fmaf(w_, v_, acc[i_]);                                   \
      s2[i_] = fmaf(v_, v_, s2[i_]);                                     \
    }                                                                    \
  } while (0)

// ---------------- Stage 2: hidden_forward (512 nodes) -------------------------
// v2: 8-phase (1 child per phase) register-staged 2-deep pipeline (T14):
// global loads for child c+2 issue while computing child c; ds_writes land
// one phase ahead; one barrier per phase. Summation order over c unchanged
// (c = 0..7 sequential fmaf) -> bit-identical accumulate.
__global__ __launch_bounds__(256) void stage2_kernel(
    const float* __restrict__ maxv_in, const int* __restrict__ idx_in,
    const float* __restrict__ mm,
    float* __restrict__ maxv_out, int* __restrict__ idx_out) {
  const int node = blockIdx.x;
  const int lane = threadIdx.x & 63;
  const int wave = threadIdx.x >> 6;
  const int tid = threadIdx.x;

  __shared__ float tA[4096], tB[4096];  // 32 KB double buffer

  const float4* src = reinterpret_cast<const float4*>(mm + (size_t)node * (8 * 4096));

  float acc[8], s2[8];
#pragma unroll
  for (int i = 0; i < 8; ++i) { acc[i] = 0.f; s2[i] = 0.f; }

  float4 rE[4], rO[4];
  LOAD_CHILD(rE, 0);
  LOAD_CHILD(rO, 1);
  STAGE_WRITE(tA, rE);
  __syncthreads();

#pragma unroll
  for (int cc = 0; cc < 8; cc += 2) {
    if (cc + 2 < 8) LOAD_CHILD(rE, cc + 2);
    COMPUTE_CHILD(cc, tA);
    STAGE_WRITE(tB, rO);
    __syncthreads();
    if (cc + 3 < 8) LOAD_CHILD(rO, cc + 3);
    COMPUTE_CHILD(cc + 1, tB);
    if (cc + 2 < 8) {
      STAGE_WRITE(tA, rE);
    }
    __syncthreads();
  }

#pragma unroll
  for (int i = 0; i < 8; ++i) {
    const int b = wave * 8 + i;
    const float val = acc[i] / (8.f * sqrtf(s2[i]) + RHO);
    const float mx = wave_max(val);
    unsigned long long t = __ballot(val == mx);
    int j0 = __ffsll((long long)t) - 1;
    if (lane == 0) {
      maxv_out[node * 32 + b] = mx;  // [node][b]
      idx_out[node * 32 + b] = j0;
    }
  }
}

// ---------------- Stage 3 + growth_argmaxi (fused; exact since round 1) -------
// v2: same 8-phase register-staged pipeline as stage2 (cuts the serial
// load->barrier->load latency chain; only 64 blocks so per-block latency is
// the wall). Epilogue unchanged.
__global__ __launch_bounds__(256) void grow_kernel(
    const float* __restrict__ maxv_in, const int* __restrict__ idx_in,
    const float* __restrict__ mm,
    const float* __restrict__ counts, float* __restrict__ out) {
  const int node = blockIdx.x;  // 64 nodes
  const int lane = threadIdx.x & 63;
  const int wave = threadIdx.x >> 6;
  const int tid = threadIdx.x;

  __shared__ float tA[4096], tB[4096];  // 32 KB double buffer
  __shared__ float hbuf[32 * 64];
  __shared__ float mxvS[32];
  __shared__ int idxS[32];
  __shared__ int trgS[32];
  __shared__ float cntS[64];
  __shared__ int sidxS[64];
  __shared__ int flagS[64];
  __shared__ int compS[64];
  __shared__ int selS[32];
  __shared__ float valS[32];
  __shared__ int keptS[1];

  const float4* src = reinterpret_cast<const float4*>(mm + (size_t)node * (8 * 4096));

  float acc[8], s2[8];
#pragma unroll
  for (int i = 0; i < 8; ++i) { acc[i] = 0.f; s2[i] = 0.f; }

  float4 rE[4], rO[4];
  LOAD_CHILD(rE, 0);
  LOAD_CHILD(rO, 1);
  STAGE_WRITE(tA, rE);
  __syncthreads();

#pragma unroll
  for (int cc = 0; cc < 8; cc += 2) {
    if (cc + 2 < 8) LOAD_CHILD(rE, cc + 2);
    COMPUTE_CHILD(cc, tA);
    STAGE_WRITE(tB, rO);
    __syncthreads();
    if (cc + 3 < 8) LOAD_CHILD(rO, cc + 3);
    COMPUTE_CHILD(cc + 1, tB);
    if (cc + 2 < 8) {
      STAGE_WRITE(tA, rE);
    }
    __syncthreads();
  }

#pragma unroll
  for (int i = 0; i < 8; ++i) {
    const int b = wave * 8 + i;
    const float val = acc[i] / (8.f * sqrtf(s2[i]) + RHO);
    const float mx = wave_max(val);
    unsigned long long t = __ballot(val == mx);
    int j0 = __ffsll((long long)t) - 1;
    hbuf[b * 64 + lane] = val;
    unsigned long long big = __ballot(val > THRESH);
    if (lane == 0) {
      mxvS[b] = mx; idxS[b] = j0; trgS[b] = (big == 0ULL) ? 1 : 0;
    }
  }

  if (tid < 64) { cntS[tid] = counts[node * 64 + tid]; flagS[tid] = 0; }
  __syncthreads();
  if (tid < 64) {  // stable ascending argsort of counts row
    float cl = cntS[tid];
    int rank = 0;
    for (int j = 0; j < 64; ++j) {
      float cj = cntS[j];
      rank += (cj < cl || (cj == cl && j < tid)) ? 1 : 0;
    }
    sidxS[rank] = tid;
  }
  __syncthreads();
  if (tid < 32) {  // reserved marks from non-triggered batches
    const int b = tid;
    if (!trgS[b]) {
      int j = idxS[b];
      float a = fabsf(mxvS[b]);
      int res;
      if (a > EPSV) res = j;             // unique positive max -> argsort[-1]=j
      else if (a == 0.f) res = 63;       // all-zero row: stable last = 63
      else if (a == EPSV) res = j;       // +inf at j
      else res = (j == 63) ? 62 : 63;    // negative entry: last zero wins
      flagS[res] = 1;
    }
  }
  __syncthreads();
  if (wave == 0) {  // stable compaction (move MARK to back)
    int s = sidxS[lane];
    int keep = flagS[s] ? 0 : 1;
    unsigned long long kb = __ballot(keep);
    int pos = __popcll(kb & ((1ULL << lane) - 1ULL));
    if (keep) compS[pos] = s;
    if (lane == 0) keptS[0] = __popcll(kb);
  }
  __syncthreads();
  if (tid < 32) {  // final index + value per batch
    const int b = tid;
    int fin = (b < keptS[0]) ? compS[b] : sidxS[b];
    int idxb; float a;
    if (trgS[b]) {
      idxb = fin;
      float v = hbuf[b * 64 + idxb];
      if (v == 0.f) v = 1.f;
      a = fabsf(v);
    } else {
      idxb = idxS[b];
      a = fabsf(mxvS[b]);
    }
    selS[b] = idxb;
    valS[b] = a / (a - EPSV);
  }
  __syncthreads();
#pragma unroll
  for (int r = 0; r < 8; ++r) {  // write (32,64) one-hot rows for this node
    int i = tid + 256 * r;
    int b = i >> 6, h = i & 63;
    out[((size_t)b * 64 + node) * 64 + h] = (h == selS[b]) ? valS[b] : 0.f;
  }
}

extern "C" void kernel_launch(void* const* d_in, const int* in_sizes, int n_in,
                              void* d_out, int out_size, void* d_ws, size_t ws_size,
                              hipStream_t stream) {
  const float* xs = (const float*)d_in[0];      // (32, 4096, 64)
  const float* mm0 = (const float*)d_in[1];     // (4096, 64, 64)
  const float* mm1 = (const float*)d_in[2];     // (512, 8, 64, 64)
  const float* mm2 = (const float*)d_in[3];     // (64, 8, 64, 64)
  const float* counts = (const float*)d_in[4];  // (64, 64)
  float* out = (float*)d_out;                   // (32, 64, 64)
  char* ws = (char*)d_ws;

  float* maxv1 = (float*)(ws + 0);        // [4096][32] f32
  int* idx1 = (int*)(ws + 524288);        // [4096][32] i32
  float* maxv2 = (float*)(ws + 1048576);  // [512][32] f32
  int* idx2 = (int*)(ws + 1114112);       // [512][32] i32

  stage1_kernel<<<dim3(2048), dim3(128), 0, stream>>>(xs, mm0, maxv1, idx1);
  stage2_kernel<<<dim3(512), dim3(256), 0, stream>>>(maxv1, idx1, mm1, maxv2, idx2);
  grow_kernel<<<dim3(64), dim3(256), 0, stream>>>(maxv2, idx2, mm2, counts, out);
}

// Round 3
// 205.947 us; speedup vs baseline: 1.0936x; 1.0440x over previous
//
#include <hip/hip_runtime.h>
#include <cstdint>
#include <cstddef>

#define RHO 1e-8f
#define EPSV 1e-8f
#define THRESH 0.9f

typedef float v2f __attribute__((ext_vector_type(2)));

__device__ __forceinline__ float wave_max(float v) {
#pragma unroll
  for (int off = 1; off < 64; off <<= 1) v = fmaxf(v, __shfl_xor(v, off, 64));
  return v;
}

// ---------------- Stage 1: outer_forward -> (maxval, argmax) per (f, b) ------
// v3: register-blocked GEMM, occupancy-first. Round-2 post-mortem: 52 KB
// LDS/block -> 2-3 blocks/CU -> 9.8% occupancy -> pure latency exposure.
// Now ONE field per 128-thread block; the 2 waves split the 64 m-rows
// (wave w owns rows 32w..32w+31) and share ONE XOR-swizzled m tile
// (16,384 B; float4 slot(r,q) = r*16 + (q ^ (r&15)) -> staging writes,
// K-loop reads and norm reads all hit 8 distinct bank-quads = minimal
// rounds) plus one x tile (8,192 B). LDS/block ~25.5 KB -> 6 blocks/CU
// = 12 waves/CU, VGPR ~115 (acc 4x4 per lane). Per lane: 4 m-rows x 4 b,
// 8 ds_read_b128 + 32 v_pk_fma per K-chunk of 4.
__global__ __launch_bounds__(128) void stage1_kernel(
    const float* __restrict__ xs, const float* __restrict__ mm0,
    float* __restrict__ maxv1, int* __restrict__ idx1) {
  const int tid = threadIdx.x;
  const int lane = tid & 63;
  const int wave = tid >> 6;
  const int f = blockIdx.x;

  __shared__ float mS[64 * 64];  // 16,384 B, swizzled float4 slots
  __shared__ float xS[32 * 64];  // 8,192 B, swizzled float4 slots
  __shared__ float mnS[64];
  __shared__ float xnS[32];
  __shared__ float bestS[2][32];
  __shared__ int bidxS[2][32];

  // ---- stage m tile (shifted by -0.5): 8 float4 per thread, coalesced ----
  const float* mf = mm0 + (size_t)f * 4096;
#pragma unroll
  for (int i = 0; i < 8; ++i) {
    const int g = tid + 128 * i;  // linear float4 index [0,1024)
    const int r = g >> 4, q = g & 15;
    float4 v = *reinterpret_cast<const float4*>(mf + g * 4);
    float4 w = {v.x - 0.5f, v.y - 0.5f, v.z - 0.5f, v.w - 0.5f};
    *reinterpret_cast<float4*>(&mS[(r * 16 + (q ^ (r & 15))) * 4]) = w;
  }
  // ---- stage x tile (shifted by -0.5): 4 float4 per thread ----
  const float* xf = xs + (size_t)f * 64;
#pragma unroll
  for (int i = 0; i < 4; ++i) {
    const int g = tid + 128 * i;  // [0,512)
    const int b = g >> 4, q = g & 15;
    float4 v = *reinterpret_cast<const float4*>(xf + (size_t)b * (4096 * 64) + q * 4);
    float4 w = {v.x - 0.5f, v.y - 0.5f, v.z - 0.5f, v.w - 0.5f};
    *reinterpret_cast<float4*>(&xS[(b * 16 + (q ^ (b & 15))) * 4]) = w;
  }
  __syncthreads();

  // ---- norms: t<64 -> m row t; t in [64,96) -> x row t-64 (one-time) ----
  if (tid < 96) {
    const int r = (tid < 64) ? tid : (tid - 64);
    const float* base = (tid < 64) ? mS : xS;
    v2f s = {0.f, 0.f};
#pragma unroll
    for (int q = 0; q < 16; ++q) {
      float4 v = *reinterpret_cast<const float4*>(&base[(r * 16 + (q ^ (r & 15))) * 4]);
      s = (v2f){v.x, v.y} * (v2f){v.x, v.y} + s;
      s = (v2f){v.z, v.w} * (v2f){v.z, v.w} + s;
    }
    const float n = sqrtf(s.x + s.y);
    if (tid < 64) mnS[r] = n; else xnS[r] = n;
  }
  __syncthreads();

  // ---- K-loop: wave w owns m rows 32w+mg+8i (i<4); lane grid 8mg x 8bg ----
  const int mg = lane >> 3, bg = lane & 7;
  const int mrow0 = wave * 32 + mg;
  v2f acc[4][4][2];
#pragma unroll
  for (int i = 0; i < 4; ++i)
#pragma unroll
    for (int j = 0; j < 4; ++j) {
      acc[i][j][0] = (v2f){0.f, 0.f};
      acc[i][j][1] = (v2f){0.f, 0.f};
    }

#pragma unroll
  for (int d0 = 0; d0 < 64; d0 += 4) {
    const int q = d0 >> 2;
    float4 a[4], bx[4];
#pragma unroll
    for (int i = 0; i < 4; ++i) {
      const int r = mrow0 + 8 * i;
      a[i] = *reinterpret_cast<const float4*>(&mS[(r * 16 + (q ^ (r & 15))) * 4]);
    }
#pragma unroll
    for (int j = 0; j < 4; ++j) {
      const int b = bg + 8 * j;
      bx[j] = *reinterpret_cast<const float4*>(&xS[(b * 16 + (q ^ (b & 15))) * 4]);
    }
#pragma unroll
    for (int i = 0; i < 4; ++i)
#pragma unroll
      for (int j = 0; j < 4; ++j) {
        acc[i][j][0] = (v2f){a[i].x, a[i].y} * (v2f){bx[j].x, bx[j].y} + acc[i][j][0];
        acc[i][j][1] = (v2f){a[i].z, a[i].w} * (v2f){bx[j].z, bx[j].w} + acc[i][j][1];
      }
  }

  // ---- norms from LDS (scalar broadcast-ish reads, 8 total) ----
  float mn_i[4], xn_j[4];
#pragma unroll
  for (int i = 0; i < 4; ++i) mn_i[i] = mnS[mrow0 + 8 * i];
#pragma unroll
  for (int j = 0; j < 4; ++j) xn_j[j] = xnS[bg + 8 * j];

  // ---- vals + in-lane argmax over i (rows ascending -> first-max) ----
  float best[4];
  int bidx[4];
#pragma unroll
  for (int j = 0; j < 4; ++j) { best[j] = -__builtin_inff(); bidx[j] = 0; }
#pragma unroll
  for (int i = 0; i < 4; ++i)
#pragma unroll
    for (int j = 0; j < 4; ++j) {
      const float dot =
          acc[i][j][0].x + acc[i][j][0].y + acc[i][j][1].x + acc[i][j][1].y;
      const float val = (dot * 0.5f) / (mn_i[i] * xn_j[j] + RHO) + 0.5f;
      if (val > best[j]) { best[j] = val; bidx[j] = mrow0 + 8 * i; }
    }
  // ---- cross-lane argmax over mg (xor 8/16/32); ties -> lower m ----
#pragma unroll
  for (int off = 8; off < 64; off <<= 1) {
#pragma unroll
    for (int j = 0; j < 4; ++j) {
      const float pv = __shfl_xor(best[j], off, 64);
      const int pm = __shfl_xor(bidx[j], off, 64);
      if (pv > best[j] || (pv == best[j] && pm < bidx[j])) {
        best[j] = pv; bidx[j] = pm;
      }
    }
  }
  if (mg == 0) {  // lanes 0..7 hold b = bg+8j
#pragma unroll
    for (int j = 0; j < 4; ++j) {
      bestS[wave][bg + 8 * j] = best[j];
      bidxS[wave][bg + 8 * j] = bidx[j];
    }
  }
  __syncthreads();
  if (tid < 32) {  // combine halves; ties -> low half (lower m indices)
    const float v0 = bestS[0][tid], v1 = bestS[1][tid];
    const int i0 = bidxS[0][tid], i1 = bidxS[1][tid];
    const bool take1 = (v1 > v0);
    maxv1[f * 32 + tid] = take1 ? v1 : v0;
    idx1[f * 32 + tid] = take1 ? i1 : i0;
  }
}

// -------- shared pipeline macros for stage2/grow (1 child = 16 KB tile) -----
// Swizzled layout per child: element (h,k) at [k*64 + (h^k)] -> staging
// writes and per-(b) column reads are conflict-free.
#define STAGE_WRITE(T, R)                                    \
  do {                                                       \
    _Pragma("unroll") for (int i_ = 0; i_ < 4; ++i_) {       \
      const int g_ = tid + 256 * i_;                         \
      const int h_ = g_ >> 4, k0_ = (g_ & 15) * 4;           \
      (T)[(k0_ + 0) * 64 + (h_ ^ (k0_ + 0))] = (R)[i_].x;    \
      (T)[(k0_ + 1) * 64 + (h_ ^ (k0_ + 1))] = (R)[i_].y;    \
      (T)[(k0_ + 2) * 64 + (h_ ^ (k0_ + 2))] = (R)[i_].z;    \
      (T)[(k0_ + 3) * 64 + (h_ ^ (k0_ + 3))] = (R)[i_].w;    \
    }                                                        \
  } while (0)

#define LOAD_CHILD(R, C)                                     \
  do {                                                       \
    _Pragma("unroll") for (int i_ = 0; i_ < 4; ++i_)         \
        (R)[i_] = src[(C) * 1024 + tid + 256 * i_];          \
  } while (0)

// v3: (k, v) come from LDS tables preloaded at block start (uniform
// broadcast reads) instead of wave-uniform GLOBAL scalar loads inside the
// barriered loop (those were 128 serialized L2/HBM round trips per wave).
#define COMPUTE_CHILD(C, T)                                              \
  do {                                                                   \
    _Pragma("unroll") for (int i_ = 0; i_ < 8; ++i_) {                   \
      const int b_ = wave * 8 + i_;                                      \
      const int k_ = ixL[(C) * 32 + b_];                                 \
      const float v_ = mvL[(C) * 32 + b_];                               \
      const float w_ = (T)[k_ * 64 + (lane ^ k_)];                       \
      acc[i_] = fmaf(w_, v_, acc[i_]);                                   \
      s2[i_] = fmaf(v_, v_, s2[i_]);                                     \
    }                                                                    \
  } while (0)

// ---------------- Stage 2: hidden_forward (512 nodes) -------------------------
// 8-phase register-staged 2-deep pipeline; summation order over c unchanged
// (c = 0..7 sequential fmaf) -> bit-identical accumulate.
__global__ __launch_bounds__(256) void stage2_kernel(
    const float* __restrict__ maxv_in, const int* __restrict__ idx_in,
    const float* __restrict__ mm,
    float* __restrict__ maxv_out, int* __restrict__ idx_out) {
  const int node = blockIdx.x;
  const int lane = threadIdx.x & 63;
  const int wave = threadIdx.x >> 6;
  const int tid = threadIdx.x;

  __shared__ float tA[4096], tB[4096];  // 32 KB double buffer
  __shared__ float mvL[256];
  __shared__ int ixL[256];

  const float4* src = reinterpret_cast<const float4*>(mm + (size_t)node * (8 * 4096));

  // preload the full (c,b) index/value table for this node (coalesced)
  mvL[tid] = maxv_in[node * 256 + tid];
  ixL[tid] = idx_in[node * 256 + tid];

  float acc[8], s2[8];
#pragma unroll
  for (int i = 0; i < 8; ++i) { acc[i] = 0.f; s2[i] = 0.f; }

  float4 rE[4], rO[4];
  LOAD_CHILD(rE, 0);
  LOAD_CHILD(rO, 1);
  STAGE_WRITE(tA, rE);
  __syncthreads();

#pragma unroll
  for (int cc = 0; cc < 8; cc += 2) {
    if (cc + 2 < 8) LOAD_CHILD(rE, cc + 2);
    COMPUTE_CHILD(cc, tA);
    STAGE_WRITE(tB, rO);
    __syncthreads();
    if (cc + 3 < 8) LOAD_CHILD(rO, cc + 3);
    COMPUTE_CHILD(cc + 1, tB);
    if (cc + 2 < 8) {
      STAGE_WRITE(tA, rE);
    }
    __syncthreads();
  }

#pragma unroll
  for (int i = 0; i < 8; ++i) {
    const int b = wave * 8 + i;
    const float val = acc[i] / (8.f * sqrtf(s2[i]) + RHO);
    const float mx = wave_max(val);
    unsigned long long t = __ballot(val == mx);
    int j0 = __ffsll((long long)t) - 1;
    if (lane == 0) {
      maxv_out[node * 32 + b] = mx;  // [node][b]
      idx_out[node * 32 + b] = j0;
    }
  }
}

// ---------------- Stage 3 + growth_argmaxi (fused; exact since round 1) -------
__global__ __launch_bounds__(256) void grow_kernel(
    const float* __restrict__ maxv_in, const int* __restrict__ idx_in,
    const float* __restrict__ mm,
    const float* __restrict__ counts, float* __restrict__ out) {
  const int node = blockIdx.x;  // 64 nodes
  const int lane = threadIdx.x & 63;
  const int wave = threadIdx.x >> 6;
  const int tid = threadIdx.x;

  __shared__ float tA[4096], tB[4096];  // 32 KB double buffer
  __shared__ float mvL[256];
  __shared__ int ixL[256];
  __shared__ float hbuf[32 * 64];
  __shared__ float mxvS[32];
  __shared__ int idxS[32];
  __shared__ int trgS[32];
  __shared__ float cntS[64];
  __shared__ int sidxS[64];
  __shared__ int flagS[64];
  __shared__ int compS[64];
  __shared__ int selS[32];
  __shared__ float valS[32];
  __shared__ int keptS[1];

  const float4* src = reinterpret_cast<const float4*>(mm + (size_t)node * (8 * 4096));

  mvL[tid] = maxv_in[node * 256 + tid];
  ixL[tid] = idx_in[node * 256 + tid];

  float acc[8], s2[8];
#pragma unroll
  for (int i = 0; i < 8; ++i) { acc[i] = 0.f; s2[i] = 0.f; }

  float4 rE[4], rO[4];
  LOAD_CHILD(rE, 0);
  LOAD_CHILD(rO, 1);
  STAGE_WRITE(tA, rE);
  __syncthreads();

#pragma unroll
  for (int cc = 0; cc < 8; cc += 2) {
    if (cc + 2 < 8) LOAD_CHILD(rE, cc + 2);
    COMPUTE_CHILD(cc, tA);
    STAGE_WRITE(tB, rO);
    __syncthreads();
    if (cc + 3 < 8) LOAD_CHILD(rO, cc + 3);
    COMPUTE_CHILD(cc + 1, tB);
    if (cc + 2 < 8) {
      STAGE_WRITE(tA, rE);
    }
    __syncthreads();
  }

#pragma unroll
  for (int i = 0; i < 8; ++i) {
    const int b = wave * 8 + i;
    const float val = acc[i] / (8.f * sqrtf(s2[i]) + RHO);
    const float mx = wave_max(val);
    unsigned long long t = __ballot(val == mx);
    int j0 = __ffsll((long long)t) - 1;
    hbuf[b * 64 + lane] = val;
    unsigned long long big = __ballot(val > THRESH);
    if (lane == 0) {
      mxvS[b] = mx; idxS[b] = j0; trgS[b] = (big == 0ULL) ? 1 : 0;
    }
  }

  if (tid < 64) { cntS[tid] = counts[node * 64 + tid]; flagS[tid] = 0; }
  __syncthreads();
  if (tid < 64) {  // stable ascending argsort of counts row
    float cl = cntS[tid];
    int rank = 0;
    for (int j = 0; j < 64; ++j) {
      float cj = cntS[j];
      rank += (cj < cl || (cj == cl && j < tid)) ? 1 : 0;
    }
    sidxS[rank] = tid;
  }
  __syncthreads();
  if (tid < 32) {  // reserved marks from non-triggered batches
    const int b = tid;
    if (!trgS[b]) {
      int j = idxS[b];
      float a = fabsf(mxvS[b]);
      int res;
      if (a > EPSV) res = j;             // unique positive max -> argsort[-1]=j
      else if (a == 0.f) res = 63;       // all-zero row: stable last = 63
      else if (a == EPSV) res = j;       // +inf at j
      else res = (j == 63) ? 62 : 63;    // negative entry: last zero wins
      flagS[res] = 1;
    }
  }
  __syncthreads();
  if (wave == 0) {  // stable compaction (move MARK to back)
    int s = sidxS[lane];
    int keep = flagS[s] ? 0 : 1;
    unsigned long long kb = __ballot(keep);
    int pos = __popcll(kb & ((1ULL << lane) - 1ULL));
    if (keep) compS[pos] = s;
    if (lane == 0) keptS[0] = __popcll(kb);
  }
  __syncthreads();
  if (tid < 32) {  // final index + value per batch
    const int b = tid;
    int fin = (b < keptS[0]) ? compS[b] : sidxS[b];
    int idxb; float a;
    if (trgS[b]) {
      idxb = fin;
      float v = hbuf[b * 64 + idxb];
      if (v == 0.f) v = 1.f;
      a = fabsf(v);
    } else {
      idxb = idxS[b];
      a = fabsf(mxvS[b]);
    }
    selS[b] = idxb;
    valS[b] = a / (a - EPSV);
  }
  __syncthreads();
#pragma unroll
  for (int r = 0; r < 8; ++r) {  // write (32,64) one-hot rows for this node
    int i = tid + 256 * r;
    int b = i >> 6, h = i & 63;
    out[((size_t)b * 64 + node) * 64 + h] = (h == selS[b]) ? valS[b] : 0.f;
  }
}

extern "C" void kernel_launch(void* const* d_in, const int* in_sizes, int n_in,
                              void* d_out, int out_size, void* d_ws, size_t ws_size,
                              hipStream_t stream) {
  const float* xs = (const float*)d_in[0];      // (32, 4096, 64)
  const float* mm0 = (const float*)d_in[1];     // (4096, 64, 64)
  const float* mm1 = (const float*)d_in[2];     // (512, 8, 64, 64)
  const float* mm2 = (const float*)d_in[3];     // (64, 8, 64, 64)
  const float* counts = (const float*)d_in[4];  // (64, 64)
  float* out = (float*)d_out;                   // (32, 64, 64)
  char* ws = (char*)d_ws;

  float* maxv1 = (float*)(ws + 0);        // [4096][32] f32
  int* idx1 = (int*)(ws + 524288);        // [4096][32] i32
  float* maxv2 = (float*)(ws + 1048576);  // [512][32] f32
  int* idx2 = (int*)(ws + 1114112);       // [512][32] i32

  stage1_kernel<<<dim3(4096), dim3(128), 0, stream>>>(xs, mm0, maxv1, idx1);
  stage2_kernel<<<dim3(512), dim3(256), 0, stream>>>(maxv1, idx1, mm1, maxv2, idx2);
  grow_kernel<<<dim3(64), dim3(256), 0, stream>>>(maxv2, idx2, mm2, counts, out);
}